// Round 11
// baseline (217.302 us; speedup 1.0000x reference)
//
#include <hip/hip_runtime.h>
#include <hip/hip_bf16.h>
#include <stdint.h>
#include <stddef.h>

#define S_LEN 2048
#define HIDDEN 2048
#define NHEAD 32
#define NKVH 8
#define DHEAD 64
#define BATCH 2
#define HALFW 512
// 0.125 (1/sqrt(64)) * log2(e) folded into Q at RoPE time
#define QSCALE 0.18033688011112042f

typedef __attribute__((ext_vector_type(4))) float f32x4;
typedef __attribute__((ext_vector_type(8))) short short8;
typedef __attribute__((ext_vector_type(4))) short short4v;
typedef __attribute__((ext_vector_type(2))) unsigned int u32x2;

__device__ __forceinline__ unsigned short f2bf(float f) {
  unsigned u = __builtin_bit_cast(unsigned, f);
  u += 0x7fffu + ((u >> 16) & 1u);
  return (unsigned short)(u >> 16);
}
__device__ __forceinline__ float bf2f(unsigned short h) {
  unsigned u = ((unsigned)h) << 16;
  return __builtin_bit_cast(float, u);
}
__device__ __forceinline__ unsigned cvt_pk_bf16(float lo, float hi) {
  unsigned r;
  asm("v_cvt_pk_bf16_f32 %0, %1, %2" : "=v"(r) : "v"(lo), "v"(hi));
  return r;
}

// ---------------- merged f32 -> bf16 convert for all 5 tensors ----------------
__global__ void k_cvt5(const float* __restrict__ s0, const float* __restrict__ s1,
                       const float* __restrict__ s2, const float* __restrict__ s3,
                       const float* __restrict__ s4,
                       unsigned short* __restrict__ d0, unsigned short* __restrict__ d1,
                       unsigned short* __restrict__ d2, unsigned short* __restrict__ d3,
                       unsigned short* __restrict__ d4) {
  int i = blockIdx.x * blockDim.x + threadIdx.x;
#pragma unroll 1
  for (int it = 0; it < 9; ++it, i += 524288) {
    const float* src;
    unsigned short* dst;
    int base;
    if (i < 2097152)      { src = s0; dst = d0; base = 0; }
    else if (i < 3145728) { src = s1; dst = d1; base = 2097152; }
    else if (i < 3407872) { src = s2; dst = d2; base = 3145728; }
    else if (i < 3670016) { src = s3; dst = d3; base = 3407872; }
    else                  { src = s4; dst = d4; base = 3670016; }
    int j = i - base;
    float4 v = reinterpret_cast<const float4*>(src)[j];
    short4v o;
    o[0] = (short)f2bf(v.x);
    o[1] = (short)f2bf(v.y);
    o[2] = (short)f2bf(v.z);
    o[3] = (short)f2bf(v.w);
    reinterpret_cast<short4v*>(dst)[j] = o;
  }
}

// ---------------- bf16 GEMM: C[M,N] = A[M,K] * W[N,K]^T ----------------
// R9-verified: m97 structure, 128x128 tile, BK=32, 4 waves, gld_lds w=16.
// Chunk-XOR LDS swizzle: physical 16B-chunk c' = c ^ ((row>>1)&3) within each
// 64B row (source fetches permuted chunk from the same 64B line; fragment
// read XORs lhi by (l15>>1)&3). Measured: 0 bank conflicts, QKV 88us.
// MODE 1: f32 store. MODE 2: fused RoPE + head-split epilogue.
template <int MODE>
__global__ __launch_bounds__(256) void k_gemm_bt(const unsigned short* __restrict__ A,
                                                 const unsigned short* __restrict__ Bw,
                                                 void* __restrict__ Cout,
                                                 const float* __restrict__ cosb,
                                                 const float* __restrict__ sinb,
                                                 unsigned short* __restrict__ Qr,
                                                 unsigned short* __restrict__ Kr,
                                                 unsigned short* __restrict__ Vrow,
                                                 int M, int N, int K) {
  __shared__ unsigned short As[128][32];
  __shared__ unsigned short Bs[128][32];
  const int tid = threadIdx.x;
  const int wid = tid >> 6;
  const int lane = tid & 63;
  const int l15 = lane & 15;
  const int lhi = lane >> 4;
  const int bm = blockIdx.y * 128;
  const int bn = blockIdx.x * 128;
  const int wm = (wid >> 1) * 64;
  const int wn = (wid & 1) * 64;
  f32x4 acc[4][4] = {};

  const int xq = (l15 >> 1) & 3;            // fragment-read chunk XOR
  const int rc0 = (lhi ^ xq) * 16;          // physical chunk byte offset

  for (int k0 = 0; k0 < K; k0 += 32) {
#pragma unroll
    for (int i = 0; i < 2; ++i) {
      int u = i * 256 + tid;          // 512 16B units per 128x32 tile
      int row = u >> 2, c8 = u & 3;
      int cs = c8 ^ ((row >> 1) & 3); // source-side chunk permutation
      const unsigned short* ga = A + (size_t)(bm + row) * K + k0 + cs * 8;
      const unsigned short* gb = Bw + (size_t)(bn + row) * K + k0 + cs * 8;
      __builtin_amdgcn_global_load_lds(
          (const __attribute__((address_space(1))) unsigned int*)(const void*)ga,
          (__attribute__((address_space(3))) unsigned int*)(void*)((char*)&As[0][0] + i * 4096 + wid * 1024),
          16, 0, 0);
      __builtin_amdgcn_global_load_lds(
          (const __attribute__((address_space(1))) unsigned int*)(const void*)gb,
          (__attribute__((address_space(3))) unsigned int*)(void*)((char*)&Bs[0][0] + i * 4096 + wid * 1024),
          16, 0, 0);
    }
    __syncthreads();   // drains vmcnt (global_load_lds) + makes tile visible

    short8 af[4], bfr[4];
#pragma unroll
    for (int m = 0; m < 4; ++m)
      af[m] = *reinterpret_cast<const short8*>(
          (const char*)&As[0][0] + (size_t)(wm + m * 16 + l15) * 64 + rc0);
#pragma unroll
    for (int n = 0; n < 4; ++n)
      bfr[n] = *reinterpret_cast<const short8*>(
          (const char*)&Bs[0][0] + (size_t)(wn + n * 16 + l15) * 64 + rc0);
#pragma unroll
    for (int m = 0; m < 4; ++m)
#pragma unroll
      for (int n = 0; n < 4; ++n)
        acc[m][n] = __builtin_amdgcn_mfma_f32_16x16x32_bf16(af[m], bfr[n], acc[m][n], 0, 0, 0);
    __syncthreads();   // all reads done before next stage overwrites
  }

  if (MODE == 1) {
#pragma unroll
    for (int m = 0; m < 4; ++m) {
#pragma unroll
      for (int r = 0; r < 4; ++r) {
        int row = bm + wm + m * 16 + lhi * 4 + r;
#pragma unroll
        for (int n = 0; n < 4; ++n) {
          int col = bn + wn + n * 16 + l15;
          ((float*)Cout)[(size_t)row * N + col] = acc[m][n][r];
        }
      }
    }
  } else {
    // MODE 2: fused RoPE + head-split epilogue
    const int hc = (bn + wn) >> 6;     // head chunk 0..47 (wave-uniform)
#pragma unroll
    for (int m = 0; m < 4; ++m) {
#pragma unroll
      for (int r = 0; r < 4; ++r) {
        int row = bm + wm + m * 16 + lhi * 4 + r;   // = b*2048 + s
        int b = row >> 11, s = row & 2047;
        if (hc < 40) {
#pragma unroll
          for (int n = 0; n < 2; ++n) {
            int d = n * 16 + l15;
            float c = cosb[(size_t)row * DHEAD + d];
            float sn = sinb[(size_t)row * DHEAD + d];
            float x1 = acc[m][n][r];
            float x2 = acc[m][n + 2][r];
            float o1 = x1 * c - x2 * sn;
            float o2 = x2 * c + x1 * sn;
            if (hc < 32) {
              size_t o = ((size_t)(b * NHEAD + hc) * S_LEN + s) * DHEAD + d;
              Qr[o] = f2bf(o1 * QSCALE);
              Qr[o + 32] = f2bf(o2 * QSCALE);
            } else {
              size_t o = ((size_t)(b * NKVH + (hc - 32)) * S_LEN + s) * DHEAD + d;
              Kr[o] = f2bf(o1);
              Kr[o + 32] = f2bf(o2);
            }
          }
        } else {
#pragma unroll
          for (int n = 0; n < 4; ++n) {
            int d = n * 16 + l15;
            size_t o = ((size_t)(b * NKVH + (hc - 40)) * S_LEN + s) * DHEAD + d;
            Vrow[o] = f2bf(acc[m][n][r]);
          }
        }
      }
    }
  }
}

// ---------------- V transpose: Vrow (b,hk,s,d) -> Vt (b,hk,d,s) ----------------
__global__ void k_vt(const unsigned short* __restrict__ Vrow, unsigned short* __restrict__ Vt) {
  __shared__ unsigned short t[64][68];   // 64 s-rows x 64 d-cols, padded
  int s0 = blockIdx.x * 64;
  int g = blockIdx.y;                    // b*8 + hk
  int tid = threadIdx.x;
#pragma unroll
  for (int it = 0; it < 4; ++it) {
    int u = it * 256 + tid;
    int srow = u >> 4, c4 = u & 15;
    short4v v = *reinterpret_cast<const short4v*>(
        &Vrow[((size_t)g * S_LEN + s0 + srow) * DHEAD + c4 * 4]);
    *reinterpret_cast<short4v*>(&t[srow][c4 * 4]) = v;
  }
  __syncthreads();
#pragma unroll
  for (int it = 0; it < 4; ++it) {
    int u = it * 256 + tid;
    int d = u >> 4, s4 = u & 15;
    short4v v;
#pragma unroll
    for (int j = 0; j < 4; ++j) v[j] = t[s4 * 4 + j][d];
    *reinterpret_cast<short4v*>(
        &Vt[((size_t)g * DHEAD + d) * S_LEN + s0 + s4 * 4]) = v;
  }
}

// ---------------- sliding-window attention (swapped-QK, packed P) ----------------
// 8 waves x 128 q-rows per block (halves per-q K/V staging + barriers vs 64-row
// blocks: window 1024+128 spans ~19 tiles for 2x the rows). Waves whose 16-row
// window misses a tile skip compute (wave-uniform guard; barriers stay
// block-uniform). LDS 48KB -> 3 blocks/CU (24 waves/CU).
__global__ __launch_bounds__(512, 6) void k_attn(const unsigned short* __restrict__ Qr,
                                                 const unsigned short* __restrict__ Kr,
                                                 const unsigned short* __restrict__ Vt,
                                                 unsigned short* __restrict__ AO) {
  __shared__ unsigned short Ks[2][64][64];   // 16 KB
  __shared__ unsigned short Vs[2][64][64];   // 16 KB
  __shared__ unsigned short Pl[8][16][64];   // 16 KB

  const int tid = threadIdx.x, w = tid >> 6, lane = tid & 63;
  const int l15 = lane & 15, lhi = lane >> 4;

  // XCD-chunked bijective swizzle: 1024 blocks, 128 consecutive logical ids
  // per XCD => 2 (b,hk) K/V working sets (~1 MB) per XCD L2.
  int p = blockIdx.x;
  int L = (p & 7) * 128 + (p >> 3);
  int g = L >> 6;                 // 16 groups: (b, hk)
  int b = g >> 3, hk = g & 7;
  int r_ = L & 63;
  int h = hk * 4 + (r_ >> 4);
  int q0b = (r_ & 15) * 128;      // block q base (128 rows)
  const int qw = q0b + w * 16;    // wave q base (16 rows)

  const unsigned short* Qh = Qr + (size_t)(b * NHEAD + h) * S_LEN * DHEAD;
  const unsigned short* Kh = Kr + (size_t)(b * NKVH + hk) * S_LEN * DHEAD;
  const unsigned short* Vh = Vt + (size_t)(b * NKVH + hk) * DHEAD * S_LEN;

  short8 qf[2];
#pragma unroll
  for (int c = 0; c < 2; ++c)
    qf[c] = *reinterpret_cast<const short8*>(&Qh[(size_t)(qw + l15) * DHEAD + c * 32 + lhi * 8]);

  f32x4 o[4] = {};
  float den = 0.f;
  const int q = qw + l15;          // this lane's q-row (swapped layout)
  const int kvisLo = q - HALFW, kvisHi = q + HALFW;

  char* plbase = (char*)&Pl[w][0][0];
  const int swzp = (l15 & 7) << 4;

  // block-uniform window (union over 128 q-rows)
  int klo = q0b - HALFW; if (klo < 0) klo = 0;
  klo &= ~63;
  int khi = q0b + 127 + HALFW; if (khi > S_LEN - 1) khi = S_LEN - 1;
  const int nt = ((khi + 1 - klo) + 63) >> 6;

  // stage one 64-key tile: 512 threads -> one 16B unit each per K and V.
  auto stage = [&](int bufidx, int kbb) {
    int u = tid;
    int row = u >> 3, c16 = u & 7;
    int sc = c16 ^ (row & 7);
    __builtin_amdgcn_global_load_lds(
        (const __attribute__((address_space(1))) unsigned int*)(const void*)
            (Kh + (size_t)(kbb + row) * DHEAD + sc * 8),
        (__attribute__((address_space(3))) unsigned int*)(void*)
            ((char*)&Ks[bufidx][0][0] + u * 16),
        16, 0, 0);
    __builtin_amdgcn_global_load_lds(
        (const __attribute__((address_space(1))) unsigned int*)(const void*)
            (Vh + (size_t)row * S_LEN + kbb + sc * 8),
        (__attribute__((address_space(3))) unsigned int*)(void*)
            ((char*)&Vs[bufidx][0][0] + u * 16),
        16, 0, 0);
  };

  int cur = 0;
  stage(0, klo);
  __syncthreads();

  for (int t = 0; t < nt; ++t) {
    const int kb = klo + t * 64;
    if (t + 1 < nt) stage(cur ^ 1, kb + 64);   // prefetch next tile

    // wave-uniform activity guard: does this tile intersect this wave's window?
    const bool act = (kb + 63 >= qw - HALFW) && (kb <= qw + 15 + HALFW);
    if (act) {
      f32x4 sacc[4] = {};
      __builtin_amdgcn_s_setprio(1);
#pragma unroll
      for (int hh = 0; hh < 4; ++hh) {
        int kr = hh * 16 + l15;
        const char* kbase = (const char*)&Ks[cur][0][0] + kr * 128;
        short8 kf0 = *reinterpret_cast<const short8*>(kbase + ((lhi ^ (kr & 7)) * 16));
        short8 kf1 = *reinterpret_cast<const short8*>(kbase + (((4 + lhi) ^ (kr & 7)) * 16));
        sacc[hh] = __builtin_amdgcn_mfma_f32_16x16x32_bf16(kf0, qf[0], sacc[hh], 0, 0, 0);
        sacc[hh] = __builtin_amdgcn_mfma_f32_16x16x32_bf16(kf1, qf[1], sacc[hh], 0, 0, 0);
      }
      __builtin_amdgcn_s_setprio(0);

      const bool inter = (kb >= qw + 15 - HALFW) && (kb + 63 <= qw + HALFW);
      if (inter) {
#pragma unroll
        for (int hh = 0; hh < 4; ++hh) {
          float p0 = __builtin_amdgcn_exp2f(sacc[hh][0]);
          float p1 = __builtin_amdgcn_exp2f(sacc[hh][1]);
          float p2 = __builtin_amdgcn_exp2f(sacc[hh][2]);
          float p3 = __builtin_amdgcn_exp2f(sacc[hh][3]);
          den += (p0 + p1) + (p2 + p3);
          u32x2 pw;
          pw[0] = cvt_pk_bf16(p0, p1);
          pw[1] = cvt_pk_bf16(p2, p3);
          *(u32x2*)(plbase + ((l15 * 128 + hh * 32 + lhi * 8) ^ swzp)) = pw;
        }
      } else {
#pragma unroll
        for (int hh = 0; hh < 4; ++hh) {
          float pp[4];
#pragma unroll
          for (int r = 0; r < 4; ++r) {
            int key = kb + hh * 16 + lhi * 4 + r;
            bool vis = (key >= kvisLo) && (key <= kvisHi);
            pp[r] = vis ? __builtin_amdgcn_exp2f(sacc[hh][r]) : 0.0f;
          }
          den += (pp[0] + pp[1]) + (pp[2] + pp[3]);
          u32x2 pw;
          pw[0] = cvt_pk_bf16(pp[0], pp[1]);
          pw[1] = cvt_pk_bf16(pp[2], pp[3]);
          *(u32x2*)(plbase + ((l15 * 128 + hh * 32 + lhi * 8) ^ swzp)) = pw;
        }
      }
      asm volatile("s_waitcnt lgkmcnt(0)" ::: "memory");
      __builtin_amdgcn_sched_barrier(0);

      short8 pf0 = *reinterpret_cast<const short8*>(plbase + ((l15 * 128 + lhi * 16) ^ swzp));
      short8 pf1 = *reinterpret_cast<const short8*>(plbase + ((l15 * 128 + 64 + lhi * 16) ^ swzp));
      __builtin_amdgcn_s_setprio(1);
#pragma unroll
      for (int c = 0; c < 4; ++c) {
        int d = c * 16 + l15;
        const char* vbase = (const char*)&Vs[cur][0][0] + d * 128;
        short8 vf0 = *reinterpret_cast<const short8*>(vbase + ((lhi ^ (d & 7)) * 16));
        short8 vf1 = *reinterpret_cast<const short8*>(vbase + (((4 + lhi) ^ (d & 7)) * 16));
        o[c] = __builtin_amdgcn_mfma_f32_16x16x32_bf16(pf0, vf0, o[c], 0, 0, 0);
        o[c] = __builtin_amdgcn_mfma_f32_16x16x32_bf16(pf1, vf1, o[c], 0, 0, 0);
      }
      __builtin_amdgcn_s_setprio(0);
    }

    __syncthreads();   // drains vmcnt (next-tile stage) + protects buffers
    cur ^= 1;
  }

  // ---- final denominator: reduce across the 4 lhi copies of each q-row ----
  den += __shfl_xor(den, 16);
  den += __shfl_xor(den, 32);

#pragma unroll
  for (int r = 0; r < 4; ++r) {
    int qo = qw + lhi * 4 + r;
    float dr = __shfl(den, lhi * 4 + r, 64);   // den lives at lanes l15 == q-row
    float dinv = 1.0f / dr;
#pragma unroll
    for (int c = 0; c < 4; ++c)
      AO[(size_t)(b * S_LEN + qo) * HIDDEN + h * DHEAD + c * 16 + l15] = f2bf(o[c][r] * dinv);
  }
}

// ---------------- host ----------------
extern "C" void kernel_launch(void* const* d_in, const int* in_sizes, int n_in,
                              void* d_out, int out_size, void* d_ws, size_t ws_size,
                              hipStream_t stream) {
  const float* hs   = (const float*)d_in[0];
  const float* cosb = (const float*)d_in[1];
  const float* sinb = (const float*)d_in[2];
  const float* Wq   = (const float*)d_in[3];
  const float* Wk   = (const float*)d_in[4];
  const float* Wv   = (const float*)d_in[5];
  const float* Wo   = (const float*)d_in[6];

  char* ws = (char*)d_ws;
  // ws layout (within the proven 62.92 MB envelope):
  unsigned short* Xbf  = (unsigned short*)(ws);                       // 16.78 MB
  unsigned short* Wqkv = (unsigned short*)(ws + 16777216);            // 12.58 MB
  unsigned short* Vt   = (unsigned short*)(ws + 29360128);            //  4.19 MB
  unsigned short* AO   = (unsigned short*)(ws + 33554432);            // 16.78 MB
  unsigned short* Wob  = (unsigned short*)(ws + 54525952);            //  8.39 MB

  // Q/K/Vrow scratch lives in d_out (25.2 MB <= 33.5 MB); dead before the
  // output projection overwrites d_out.
  unsigned short* Qr   = (unsigned short*)d_out;                      // 16.78 MB
  unsigned short* Kr   = Qr + (size_t)BATCH * NKVH * S_LEN * DHEAD * 4; // 4.19 MB
  unsigned short* Vrow = Kr + (size_t)BATCH * NKVH * S_LEN * DHEAD;     // 4.19 MB

  // converts (single merged launch)
  k_cvt5<<<2048, 256, 0, stream>>>(hs, Wq, Wk, Wv, Wo,
                                   Xbf, Wqkv, Wqkv + 4194304, Wqkv + 5242880, Wob);

  // QKV projection (4096 x 2048) @ (3072 x 2048)^T with fused RoPE/head-split
  k_gemm_bt<2><<<dim3(3072 / 128, 4096 / 128), 256, 0, stream>>>(
      Xbf, Wqkv, nullptr, cosb, sinb, Qr, Kr, Vrow, 4096, 3072, 2048);

  // V transpose (b,hk,s,d) -> (b,hk,d,s)
  k_vt<<<dim3(S_LEN / 64, BATCH * NKVH), 256, 0, stream>>>(Vrow, Vt);

  // attention: 1024 blocks x 512 threads (XCD-swizzled inside), 128 q-rows/block
  k_attn<<<BATCH * NHEAD * (S_LEN / 128), 512, 0, stream>>>(Qr, Kr, Vt, AO);

  // output projection: (4096 x 2048) @ (2048 x 2048)^T -> f32 d_out
  k_gemm_bt<1><<<dim3(2048 / 128, 4096 / 128), 256, 0, stream>>>(
      AO, Wob, d_out, nullptr, nullptr, nullptr, nullptr, nullptr, 4096, 2048, 2048);
}

// Round 12
// 212.380 us; speedup vs baseline: 1.0232x; 1.0232x over previous
//
#include <hip/hip_runtime.h>
#include <hip/hip_bf16.h>
#include <stdint.h>
#include <stddef.h>

#define S_LEN 2048
#define HIDDEN 2048
#define NHEAD 32
#define NKVH 8
#define DHEAD 64
#define BATCH 2
#define HALFW 512
// 0.125 (1/sqrt(64)) * log2(e) folded into Q at RoPE time
#define QSCALE 0.18033688011112042f

typedef __attribute__((ext_vector_type(4))) float f32x4;
typedef __attribute__((ext_vector_type(8))) short short8;
typedef __attribute__((ext_vector_type(4))) short short4v;
typedef __attribute__((ext_vector_type(2))) unsigned int u32x2;

__device__ __forceinline__ unsigned short f2bf(float f) {
  unsigned u = __builtin_bit_cast(unsigned, f);
  u += 0x7fffu + ((u >> 16) & 1u);
  return (unsigned short)(u >> 16);
}
__device__ __forceinline__ float bf2f(unsigned short h) {
  unsigned u = ((unsigned)h) << 16;
  return __builtin_bit_cast(float, u);
}
__device__ __forceinline__ unsigned cvt_pk_bf16(float lo, float hi) {
  unsigned r;
  asm("v_cvt_pk_bf16_f32 %0, %1, %2" : "=v"(r) : "v"(lo), "v"(hi));
  return r;
}

// ---------------- merged f32 -> bf16 convert for all 5 tensors ----------------
__global__ void k_cvt5(const float* __restrict__ s0, const float* __restrict__ s1,
                       const float* __restrict__ s2, const float* __restrict__ s3,
                       const float* __restrict__ s4,
                       unsigned short* __restrict__ d0, unsigned short* __restrict__ d1,
                       unsigned short* __restrict__ d2, unsigned short* __restrict__ d3,
                       unsigned short* __restrict__ d4) {
  int i = blockIdx.x * blockDim.x + threadIdx.x;
#pragma unroll 1
  for (int it = 0; it < 9; ++it, i += 524288) {
    const float* src;
    unsigned short* dst;
    int base;
    if (i < 2097152)      { src = s0; dst = d0; base = 0; }
    else if (i < 3145728) { src = s1; dst = d1; base = 2097152; }
    else if (i < 3407872) { src = s2; dst = d2; base = 3145728; }
    else if (i < 3670016) { src = s3; dst = d3; base = 3407872; }
    else                  { src = s4; dst = d4; base = 3670016; }
    int j = i - base;
    float4 v = reinterpret_cast<const float4*>(src)[j];
    short4v o;
    o[0] = (short)f2bf(v.x);
    o[1] = (short)f2bf(v.y);
    o[2] = (short)f2bf(v.z);
    o[3] = (short)f2bf(v.w);
    reinterpret_cast<short4v*>(dst)[j] = o;
  }
}

// ---------------- bf16 GEMM: C[M,N] = A[M,K] * W[N,K]^T ----------------
// R9-verified: m97 structure, 128x128 tile, BK=32, 4 waves, gld_lds w=16.
// Chunk-XOR LDS swizzle: physical 16B-chunk c' = c ^ ((row>>1)&3) within each
// 64B row (source fetches permuted chunk from the same 64B line; fragment
// read XORs lhi by (l15>>1)&3). Measured: 0 bank conflicts, QKV 88us.
// MODE 1: f32 store. MODE 2: fused RoPE + head-split epilogue.
template <int MODE>
__global__ __launch_bounds__(256) void k_gemm_bt(const unsigned short* __restrict__ A,
                                                 const unsigned short* __restrict__ Bw,
                                                 void* __restrict__ Cout,
                                                 const float* __restrict__ cosb,
                                                 const float* __restrict__ sinb,
                                                 unsigned short* __restrict__ Qr,
                                                 unsigned short* __restrict__ Kr,
                                                 unsigned short* __restrict__ Vrow,
                                                 int M, int N, int K) {
  __shared__ unsigned short As[128][32];
  __shared__ unsigned short Bs[128][32];
  const int tid = threadIdx.x;
  const int wid = tid >> 6;
  const int lane = tid & 63;
  const int l15 = lane & 15;
  const int lhi = lane >> 4;
  const int bm = blockIdx.y * 128;
  const int bn = blockIdx.x * 128;
  const int wm = (wid >> 1) * 64;
  const int wn = (wid & 1) * 64;
  f32x4 acc[4][4] = {};

  const int xq = (l15 >> 1) & 3;            // fragment-read chunk XOR
  const int rc0 = (lhi ^ xq) * 16;          // physical chunk byte offset

  for (int k0 = 0; k0 < K; k0 += 32) {
#pragma unroll
    for (int i = 0; i < 2; ++i) {
      int u = i * 256 + tid;          // 512 16B units per 128x32 tile
      int row = u >> 2, c8 = u & 3;
      int cs = c8 ^ ((row >> 1) & 3); // source-side chunk permutation
      const unsigned short* ga = A + (size_t)(bm + row) * K + k0 + cs * 8;
      const unsigned short* gb = Bw + (size_t)(bn + row) * K + k0 + cs * 8;
      __builtin_amdgcn_global_load_lds(
          (const __attribute__((address_space(1))) unsigned int*)(const void*)ga,
          (__attribute__((address_space(3))) unsigned int*)(void*)((char*)&As[0][0] + i * 4096 + wid * 1024),
          16, 0, 0);
      __builtin_amdgcn_global_load_lds(
          (const __attribute__((address_space(1))) unsigned int*)(const void*)gb,
          (__attribute__((address_space(3))) unsigned int*)(void*)((char*)&Bs[0][0] + i * 4096 + wid * 1024),
          16, 0, 0);
    }
    __syncthreads();   // drains vmcnt (global_load_lds) + makes tile visible

    short8 af[4], bfr[4];
#pragma unroll
    for (int m = 0; m < 4; ++m)
      af[m] = *reinterpret_cast<const short8*>(
          (const char*)&As[0][0] + (size_t)(wm + m * 16 + l15) * 64 + rc0);
#pragma unroll
    for (int n = 0; n < 4; ++n)
      bfr[n] = *reinterpret_cast<const short8*>(
          (const char*)&Bs[0][0] + (size_t)(wn + n * 16 + l15) * 64 + rc0);
#pragma unroll
    for (int m = 0; m < 4; ++m)
#pragma unroll
      for (int n = 0; n < 4; ++n)
        acc[m][n] = __builtin_amdgcn_mfma_f32_16x16x32_bf16(af[m], bfr[n], acc[m][n], 0, 0, 0);
    __syncthreads();   // all reads done before next stage overwrites
  }

  if (MODE == 1) {
#pragma unroll
    for (int m = 0; m < 4; ++m) {
#pragma unroll
      for (int r = 0; r < 4; ++r) {
        int row = bm + wm + m * 16 + lhi * 4 + r;
#pragma unroll
        for (int n = 0; n < 4; ++n) {
          int col = bn + wn + n * 16 + l15;
          ((float*)Cout)[(size_t)row * N + col] = acc[m][n][r];
        }
      }
    }
  } else {
    // MODE 2: fused RoPE + head-split epilogue
    const int hc = (bn + wn) >> 6;     // head chunk 0..47 (wave-uniform)
#pragma unroll
    for (int m = 0; m < 4; ++m) {
#pragma unroll
      for (int r = 0; r < 4; ++r) {
        int row = bm + wm + m * 16 + lhi * 4 + r;   // = b*2048 + s
        int b = row >> 11, s = row & 2047;
        if (hc < 40) {
#pragma unroll
          for (int n = 0; n < 2; ++n) {
            int d = n * 16 + l15;
            float c = cosb[(size_t)row * DHEAD + d];
            float sn = sinb[(size_t)row * DHEAD + d];
            float x1 = acc[m][n][r];
            float x2 = acc[m][n + 2][r];
            float o1 = x1 * c - x2 * sn;
            float o2 = x2 * c + x1 * sn;
            if (hc < 32) {
              size_t o = ((size_t)(b * NHEAD + hc) * S_LEN + s) * DHEAD + d;
              Qr[o] = f2bf(o1 * QSCALE);
              Qr[o + 32] = f2bf(o2 * QSCALE);
            } else {
              size_t o = ((size_t)(b * NKVH + (hc - 32)) * S_LEN + s) * DHEAD + d;
              Kr[o] = f2bf(o1);
              Kr[o + 32] = f2bf(o2);
            }
          }
        } else {
#pragma unroll
          for (int n = 0; n < 4; ++n) {
            int d = n * 16 + l15;
            size_t o = ((size_t)(b * NKVH + (hc - 40)) * S_LEN + s) * DHEAD + d;
            Vrow[o] = f2bf(acc[m][n][r]);
          }
        }
      }
    }
  }
}

// ---------------- V transpose: Vrow (b,hk,s,d) -> Vt (b,hk,d,s) ----------------
__global__ void k_vt(const unsigned short* __restrict__ Vrow, unsigned short* __restrict__ Vt) {
  __shared__ unsigned short t[64][68];   // 64 s-rows x 64 d-cols, padded
  int s0 = blockIdx.x * 64;
  int g = blockIdx.y;                    // b*8 + hk
  int tid = threadIdx.x;
#pragma unroll
  for (int it = 0; it < 4; ++it) {
    int u = it * 256 + tid;
    int srow = u >> 4, c4 = u & 15;
    short4v v = *reinterpret_cast<const short4v*>(
        &Vrow[((size_t)g * S_LEN + s0 + srow) * DHEAD + c4 * 4]);
    *reinterpret_cast<short4v*>(&t[srow][c4 * 4]) = v;
  }
  __syncthreads();
#pragma unroll
  for (int it = 0; it < 4; ++it) {
    int u = it * 256 + tid;
    int d = u >> 4, s4 = u & 15;
    short4v v;
#pragma unroll
    for (int j = 0; j < 4; ++j) v[j] = t[s4 * 4 + j][d];
    *reinterpret_cast<short4v*>(
        &Vt[((size_t)g * DHEAD + d) * S_LEN + s0 + s4 * 4]) = v;
  }
}

// ---------------- sliding-window attention (swapped-QK, packed P, GQA pair) ----
// Block = 64 q-rows x 2 heads of the SAME GQA group (8 waves, 512 threads):
// wave w -> head h0+(w>>2), rows q0b+(w&3)*16. All waves share one q-range ->
// block-uniform window, no guards; K/V staged ONCE per block serves 2 heads
// (staging per unit of MFMA work halved vs 1-head blocks).
// LDS 48KB -> 3 blocks/CU (24 waves/CU).
__global__ __launch_bounds__(512, 6) void k_attn(const unsigned short* __restrict__ Qr,
                                                 const unsigned short* __restrict__ Kr,
                                                 const unsigned short* __restrict__ Vt,
                                                 unsigned short* __restrict__ AO) {
  __shared__ unsigned short Ks[2][64][64];   // 16 KB
  __shared__ unsigned short Vs[2][64][64];   // 16 KB
  __shared__ unsigned short Pl[8][16][64];   // 16 KB

  const int tid = threadIdx.x, w = tid >> 6, lane = tid & 63;
  const int l15 = lane & 15, lhi = lane >> 4;

  // XCD-chunked bijective swizzle: 1024 blocks, 128 consecutive logical ids
  // per XCD => 2 (b,hk) K/V working sets (~1 MB) per XCD L2.
  // Per (b,hk) group: 2 head-pairs x 32 q-positions = 64 blocks.
  int p = blockIdx.x;
  int L = (p & 7) * 128 + (p >> 3);
  int g = L >> 6;                 // 16 groups: (b, hk)
  int b = g >> 3, hk = g & 7;
  int r_ = L & 63;
  int h0 = hk * 4 + (r_ >> 5) * 2;  // head pair base (within the GQA group)
  int q0b = (r_ & 31) * 64;         // block q base (64 rows)

  const int h = h0 + (w >> 2);      // this wave's head
  const int qw = q0b + (w & 3) * 16;  // this wave's q base

  const unsigned short* Qh = Qr + (size_t)(b * NHEAD + h) * S_LEN * DHEAD;
  const unsigned short* Kh = Kr + (size_t)(b * NKVH + hk) * S_LEN * DHEAD;
  const unsigned short* Vh = Vt + (size_t)(b * NKVH + hk) * DHEAD * S_LEN;

  short8 qf[2];
#pragma unroll
  for (int c = 0; c < 2; ++c)
    qf[c] = *reinterpret_cast<const short8*>(&Qh[(size_t)(qw + l15) * DHEAD + c * 32 + lhi * 8]);

  f32x4 o[4] = {};
  float den = 0.f;
  const int q = qw + l15;          // this lane's q-row (swapped layout)
  const int kvisLo = q - HALFW, kvisHi = q + HALFW;

  char* plbase = (char*)&Pl[w][0][0];
  const int swzp = (l15 & 7) << 4;

  // block-uniform window (union over 64 q-rows); tiles 64-aligned
  int klo = q0b - HALFW; if (klo < 0) klo = 0;
  klo &= ~63;
  int khi = q0b + 63 + HALFW; if (khi > S_LEN - 1) khi = S_LEN - 1;
  const int nt = ((khi + 1 - klo) + 63) >> 6;

  // stage one 64-key tile: 512 threads -> one 16B unit each per K and V.
  auto stage = [&](int bufidx, int kbb) {
    int u = tid;
    int row = u >> 3, c16 = u & 7;
    int sc = c16 ^ (row & 7);
    __builtin_amdgcn_global_load_lds(
        (const __attribute__((address_space(1))) unsigned int*)(const void*)
            (Kh + (size_t)(kbb + row) * DHEAD + sc * 8),
        (__attribute__((address_space(3))) unsigned int*)(void*)
            ((char*)&Ks[bufidx][0][0] + u * 16),
        16, 0, 0);
    __builtin_amdgcn_global_load_lds(
        (const __attribute__((address_space(1))) unsigned int*)(const void*)
            (Vh + (size_t)row * S_LEN + kbb + sc * 8),
        (__attribute__((address_space(3))) unsigned int*)(void*)
            ((char*)&Vs[bufidx][0][0] + u * 16),
        16, 0, 0);
  };

  int cur = 0;
  stage(0, klo);
  __syncthreads();

  for (int t = 0; t < nt; ++t) {
    const int kb = klo + t * 64;
    if (t + 1 < nt) stage(cur ^ 1, kb + 64);   // prefetch next tile

    // ---- QK^T (swapped): C[key][q], lane holds q=l15, keys 16hh+4lhi+r ----
    f32x4 sacc[4] = {};
    __builtin_amdgcn_s_setprio(1);
#pragma unroll
    for (int hh = 0; hh < 4; ++hh) {
      int kr = hh * 16 + l15;
      const char* kbase = (const char*)&Ks[cur][0][0] + kr * 128;
      short8 kf0 = *reinterpret_cast<const short8*>(kbase + ((lhi ^ (kr & 7)) * 16));
      short8 kf1 = *reinterpret_cast<const short8*>(kbase + (((4 + lhi) ^ (kr & 7)) * 16));
      sacc[hh] = __builtin_amdgcn_mfma_f32_16x16x32_bf16(kf0, qf[0], sacc[hh], 0, 0, 0);
      sacc[hh] = __builtin_amdgcn_mfma_f32_16x16x32_bf16(kf1, qf[1], sacc[hh], 0, 0, 0);
    }
    __builtin_amdgcn_s_setprio(0);

    const bool inter = (kb >= qw + 15 - HALFW) && (kb + 63 <= qw + HALFW);
    if (inter) {
#pragma unroll
      for (int hh = 0; hh < 4; ++hh) {
        float p0 = __builtin_amdgcn_exp2f(sacc[hh][0]);
        float p1 = __builtin_amdgcn_exp2f(sacc[hh][1]);
        float p2 = __builtin_amdgcn_exp2f(sacc[hh][2]);
        float p3 = __builtin_amdgcn_exp2f(sacc[hh][3]);
        den += (p0 + p1) + (p2 + p3);
        u32x2 pw;
        pw[0] = cvt_pk_bf16(p0, p1);
        pw[1] = cvt_pk_bf16(p2, p3);
        *(u32x2*)(plbase + ((l15 * 128 + hh * 32 + lhi * 8) ^ swzp)) = pw;
      }
    } else {
#pragma unroll
      for (int hh = 0; hh < 4; ++hh) {
        float pp[4];
#pragma unroll
        for (int r = 0; r < 4; ++r) {
          int key = kb + hh * 16 + lhi * 4 + r;
          bool vis = (key >= kvisLo) && (key <= kvisHi);
          pp[r] = vis ? __builtin_amdgcn_exp2f(sacc[hh][r]) : 0.0f;
        }
        den += (pp[0] + pp[1]) + (pp[2] + pp[3]);
        u32x2 pw;
        pw[0] = cvt_pk_bf16(pp[0], pp[1]);
        pw[1] = cvt_pk_bf16(pp[2], pp[3]);
        *(u32x2*)(plbase + ((l15 * 128 + hh * 32 + lhi * 8) ^ swzp)) = pw;
      }
    }
    asm volatile("s_waitcnt lgkmcnt(0)" ::: "memory");
    __builtin_amdgcn_sched_barrier(0);

    // ---- PV: A = P (16q x 64k) from swizzled Pl, B = V from swizzled LDS ----
    short8 pf0 = *reinterpret_cast<const short8*>(plbase + ((l15 * 128 + lhi * 16) ^ swzp));
    short8 pf1 = *reinterpret_cast<const short8*>(plbase + ((l15 * 128 + 64 + lhi * 16) ^ swzp));
    __builtin_amdgcn_s_setprio(1);
#pragma unroll
    for (int c = 0; c < 4; ++c) {
      int d = c * 16 + l15;
      const char* vbase = (const char*)&Vs[cur][0][0] + d * 128;
      short8 vf0 = *reinterpret_cast<const short8*>(vbase + ((lhi ^ (d & 7)) * 16));
      short8 vf1 = *reinterpret_cast<const short8*>(vbase + (((4 + lhi) ^ (d & 7)) * 16));
      o[c] = __builtin_amdgcn_mfma_f32_16x16x32_bf16(pf0, vf0, o[c], 0, 0, 0);
      o[c] = __builtin_amdgcn_mfma_f32_16x16x32_bf16(pf1, vf1, o[c], 0, 0, 0);
    }
    __builtin_amdgcn_s_setprio(0);

    __syncthreads();   // drains vmcnt (next-tile stage) + protects buffers
    cur ^= 1;
  }

  // ---- final denominator: reduce across the 4 lhi copies of each q-row ----
  den += __shfl_xor(den, 16);
  den += __shfl_xor(den, 32);

#pragma unroll
  for (int r = 0; r < 4; ++r) {
    int qo = qw + lhi * 4 + r;
    float dr = __shfl(den, lhi * 4 + r, 64);   // den lives at lanes l15 == q-row
    float dinv = 1.0f / dr;
#pragma unroll
    for (int c = 0; c < 4; ++c)
      AO[(size_t)(b * S_LEN + qo) * HIDDEN + h * DHEAD + c * 16 + l15] = f2bf(o[c][r] * dinv);
  }
}

// ---------------- host ----------------
extern "C" void kernel_launch(void* const* d_in, const int* in_sizes, int n_in,
                              void* d_out, int out_size, void* d_ws, size_t ws_size,
                              hipStream_t stream) {
  const float* hs   = (const float*)d_in[0];
  const float* cosb = (const float*)d_in[1];
  const float* sinb = (const float*)d_in[2];
  const float* Wq   = (const float*)d_in[3];
  const float* Wk   = (const float*)d_in[4];
  const float* Wv   = (const float*)d_in[5];
  const float* Wo   = (const float*)d_in[6];

  char* ws = (char*)d_ws;
  // ws layout (within the proven 62.92 MB envelope):
  unsigned short* Xbf  = (unsigned short*)(ws);                       // 16.78 MB
  unsigned short* Wqkv = (unsigned short*)(ws + 16777216);            // 12.58 MB
  unsigned short* Vt   = (unsigned short*)(ws + 29360128);            //  4.19 MB
  unsigned short* AO   = (unsigned short*)(ws + 33554432);            // 16.78 MB
  unsigned short* Wob  = (unsigned short*)(ws + 54525952);            //  8.39 MB

  // Q/K/Vrow scratch lives in d_out (25.2 MB <= 33.5 MB); dead before the
  // output projection overwrites d_out.
  unsigned short* Qr   = (unsigned short*)d_out;                      // 16.78 MB
  unsigned short* Kr   = Qr + (size_t)BATCH * NKVH * S_LEN * DHEAD * 4; // 4.19 MB
  unsigned short* Vrow = Kr + (size_t)BATCH * NKVH * S_LEN * DHEAD;     // 4.19 MB

  // converts (single merged launch)
  k_cvt5<<<2048, 256, 0, stream>>>(hs, Wq, Wk, Wv, Wo,
                                   Xbf, Wqkv, Wqkv + 4194304, Wqkv + 5242880, Wob);

  // QKV projection (4096 x 2048) @ (3072 x 2048)^T with fused RoPE/head-split
  k_gemm_bt<2><<<dim3(3072 / 128, 4096 / 128), 256, 0, stream>>>(
      Xbf, Wqkv, nullptr, cosb, sinb, Qr, Kr, Vrow, 4096, 3072, 2048);

  // V transpose (b,hk,s,d) -> (b,hk,d,s)
  k_vt<<<dim3(S_LEN / 64, BATCH * NKVH), 256, 0, stream>>>(Vrow, Vt);

  // attention: 1024 blocks x 512 threads (XCD-swizzled inside),
  // 64 q-rows x 2 GQA-paired heads per block
  k_attn<<<BATCH * (NHEAD / 2) * (S_LEN / 64), 512, 0, stream>>>(Qr, Kr, Vt, AO);

  // output projection: (4096 x 2048) @ (2048 x 2048)^T -> f32 d_out
  k_gemm_bt<1><<<dim3(2048 / 128, 4096 / 128), 256, 0, stream>>>(
      AO, Wob, d_out, nullptr, nullptr, nullptr, nullptr, nullptr, 4096, 2048, 2048);
}

// Round 13
// 192.107 us; speedup vs baseline: 1.1311x; 1.1055x over previous
//
#include <hip/hip_runtime.h>
#include <hip/hip_bf16.h>
#include <stdint.h>
#include <stddef.h>

#define S_LEN 2048
#define HIDDEN 2048
#define NHEAD 32
#define NKVH 8
#define DHEAD 64
#define BATCH 2
#define HALFW 512
// 0.125 (1/sqrt(64)) * log2(e) folded into Q at RoPE time
#define QSCALE 0.18033688011112042f

typedef __attribute__((ext_vector_type(4))) float f32x4;
typedef __attribute__((ext_vector_type(8))) short short8;
typedef __attribute__((ext_vector_type(4))) short short4v;
typedef __attribute__((ext_vector_type(2))) unsigned int u32x2;

__device__ __forceinline__ unsigned short f2bf(float f) {
  unsigned u = __builtin_bit_cast(unsigned, f);
  u += 0x7fffu + ((u >> 16) & 1u);
  return (unsigned short)(u >> 16);
}
__device__ __forceinline__ float bf2f(unsigned short h) {
  unsigned u = ((unsigned)h) << 16;
  return __builtin_bit_cast(float, u);
}
__device__ __forceinline__ unsigned cvt_pk_bf16(float lo, float hi) {
  unsigned r;
  asm("v_cvt_pk_bf16_f32 %0, %1, %2" : "=v"(r) : "v"(lo), "v"(hi));
  return r;
}

// ---------------- merged f32 -> bf16 convert for all 5 tensors ----------------
__global__ void k_cvt5(const float* __restrict__ s0, const float* __restrict__ s1,
                       const float* __restrict__ s2, const float* __restrict__ s3,
                       const float* __restrict__ s4,
                       unsigned short* __restrict__ d0, unsigned short* __restrict__ d1,
                       unsigned short* __restrict__ d2, unsigned short* __restrict__ d3,
                       unsigned short* __restrict__ d4) {
  int i = blockIdx.x * blockDim.x + threadIdx.x;
#pragma unroll 1
  for (int it = 0; it < 9; ++it, i += 524288) {
    const float* src;
    unsigned short* dst;
    int base;
    if (i < 2097152)      { src = s0; dst = d0; base = 0; }
    else if (i < 3145728) { src = s1; dst = d1; base = 2097152; }
    else if (i < 3407872) { src = s2; dst = d2; base = 3145728; }
    else if (i < 3670016) { src = s3; dst = d3; base = 3407872; }
    else                  { src = s4; dst = d4; base = 3670016; }
    int j = i - base;
    float4 v = reinterpret_cast<const float4*>(src)[j];
    short4v o;
    o[0] = (short)f2bf(v.x);
    o[1] = (short)f2bf(v.y);
    o[2] = (short)f2bf(v.z);
    o[3] = (short)f2bf(v.w);
    reinterpret_cast<short4v*>(dst)[j] = o;
  }
}

// ---------------- bf16 GEMM: C[M,N] = A[M,K] * W[N,K]^T ----------------
// R13: m97 tile geometry (128x128, BK=32, 4 waves) with the k_attn staging
// pattern: double-buffered LDS, prefetch tile k+1 issued BEFORE computing
// tile k, ONE __syncthreads per K-step (its implicit vmcnt drain retires the
// prefetch after it had the whole ds_read+MFMA phase to land). Chunk-XOR
// swizzle (R9-verified 0 conflicts): chunk c' = c ^ ((row>>1)&3) in each 64B
// row, permuted on the SOURCE side; fragment read XORs lhi by (l15>>1)&3.
// MODE 1: f32 store. MODE 2: fused RoPE + head-split epilogue.
template <int MODE>
__global__ __launch_bounds__(256) void k_gemm_bt(const unsigned short* __restrict__ A,
                                                 const unsigned short* __restrict__ Bw,
                                                 void* __restrict__ Cout,
                                                 const float* __restrict__ cosb,
                                                 const float* __restrict__ sinb,
                                                 unsigned short* __restrict__ Qr,
                                                 unsigned short* __restrict__ Kr,
                                                 unsigned short* __restrict__ Vrow,
                                                 int M, int N, int K) {
  __shared__ unsigned short As[2][128][32];   // 2 x 8 KB
  __shared__ unsigned short Bs[2][128][32];
  const int tid = threadIdx.x;
  const int wid = tid >> 6;
  const int lane = tid & 63;
  const int l15 = lane & 15;
  const int lhi = lane >> 4;
  const int bm = blockIdx.y * 128;
  const int bn = blockIdx.x * 128;
  const int wm = (wid >> 1) * 64;
  const int wn = (wid & 1) * 64;
  f32x4 acc[4][4] = {};

  const int xq = (l15 >> 1) & 3;            // fragment-read chunk XOR
  const int rc0 = (lhi ^ xq) * 16;          // physical chunk byte offset

  // stage one 128x32 K-tile into buffer `buf` (R9-verbatim pattern)
  auto stage = [&](int buf, int k0) {
#pragma unroll
    for (int i = 0; i < 2; ++i) {
      int u = i * 256 + tid;          // 512 16B units per 128x32 tile
      int row = u >> 2, c8 = u & 3;
      int cs = c8 ^ ((row >> 1) & 3); // source-side chunk permutation
      const unsigned short* ga = A + (size_t)(bm + row) * K + k0 + cs * 8;
      const unsigned short* gb = Bw + (size_t)(bn + row) * K + k0 + cs * 8;
      __builtin_amdgcn_global_load_lds(
          (const __attribute__((address_space(1))) unsigned int*)(const void*)ga,
          (__attribute__((address_space(3))) unsigned int*)(void*)
              ((char*)&As[0][0][0] + buf * 8192 + i * 4096 + wid * 1024),
          16, 0, 0);
      __builtin_amdgcn_global_load_lds(
          (const __attribute__((address_space(1))) unsigned int*)(const void*)gb,
          (__attribute__((address_space(3))) unsigned int*)(void*)
              ((char*)&Bs[0][0][0] + buf * 8192 + i * 4096 + wid * 1024),
          16, 0, 0);
    }
  };

  stage(0, 0);
  __syncthreads();
  int cur = 0;

  for (int k0 = 0; k0 < K; k0 += 32) {
    if (k0 + 32 < K) stage(cur ^ 1, k0 + 32);   // prefetch next tile (in flight across compute)

    const char* aB = (const char*)&As[0][0][0] + cur * 8192;
    const char* bB = (const char*)&Bs[0][0][0] + cur * 8192;
    short8 af[4], bfr[4];
#pragma unroll
    for (int m = 0; m < 4; ++m)
      af[m] = *reinterpret_cast<const short8*>(aB + (size_t)(wm + m * 16 + l15) * 64 + rc0);
#pragma unroll
    for (int n = 0; n < 4; ++n)
      bfr[n] = *reinterpret_cast<const short8*>(bB + (size_t)(wn + n * 16 + l15) * 64 + rc0);
#pragma unroll
    for (int m = 0; m < 4; ++m)
#pragma unroll
      for (int n = 0; n < 4; ++n)
        acc[m][n] = __builtin_amdgcn_mfma_f32_16x16x32_bf16(af[m], bfr[n], acc[m][n], 0, 0, 0);

    __syncthreads();   // drains vmcnt (prefetch) + all reads of buf cur done
    cur ^= 1;
  }

  if (MODE == 1) {
#pragma unroll
    for (int m = 0; m < 4; ++m) {
#pragma unroll
      for (int r = 0; r < 4; ++r) {
        int row = bm + wm + m * 16 + lhi * 4 + r;
#pragma unroll
        for (int n = 0; n < 4; ++n) {
          int col = bn + wn + n * 16 + l15;
          ((float*)Cout)[(size_t)row * N + col] = acc[m][n][r];
        }
      }
    }
  } else {
    // MODE 2: fused RoPE + head-split epilogue
    const int hc = (bn + wn) >> 6;     // head chunk 0..47 (wave-uniform)
#pragma unroll
    for (int m = 0; m < 4; ++m) {
#pragma unroll
      for (int r = 0; r < 4; ++r) {
        int row = bm + wm + m * 16 + lhi * 4 + r;   // = b*2048 + s
        int b = row >> 11, s = row & 2047;
        if (hc < 40) {
#pragma unroll
          for (int n = 0; n < 2; ++n) {
            int d = n * 16 + l15;
            float c = cosb[(size_t)row * DHEAD + d];
            float sn = sinb[(size_t)row * DHEAD + d];
            float x1 = acc[m][n][r];
            float x2 = acc[m][n + 2][r];
            float o1 = x1 * c - x2 * sn;
            float o2 = x2 * c + x1 * sn;
            if (hc < 32) {
              size_t o = ((size_t)(b * NHEAD + hc) * S_LEN + s) * DHEAD + d;
              Qr[o] = f2bf(o1 * QSCALE);
              Qr[o + 32] = f2bf(o2 * QSCALE);
            } else {
              size_t o = ((size_t)(b * NKVH + (hc - 32)) * S_LEN + s) * DHEAD + d;
              Kr[o] = f2bf(o1);
              Kr[o + 32] = f2bf(o2);
            }
          }
        } else {
#pragma unroll
          for (int n = 0; n < 4; ++n) {
            int d = n * 16 + l15;
            size_t o = ((size_t)(b * NKVH + (hc - 40)) * S_LEN + s) * DHEAD + d;
            Vrow[o] = f2bf(acc[m][n][r]);
          }
        }
      }
    }
  }
}

// ---------------- V transpose: Vrow (b,hk,s,d) -> Vt (b,hk,d,s) ----------------
__global__ void k_vt(const unsigned short* __restrict__ Vrow, unsigned short* __restrict__ Vt) {
  __shared__ unsigned short t[64][68];   // 64 s-rows x 64 d-cols, padded
  int s0 = blockIdx.x * 64;
  int g = blockIdx.y;                    // b*8 + hk
  int tid = threadIdx.x;
#pragma unroll
  for (int it = 0; it < 4; ++it) {
    int u = it * 256 + tid;
    int srow = u >> 4, c4 = u & 15;
    short4v v = *reinterpret_cast<const short4v*>(
        &Vrow[((size_t)g * S_LEN + s0 + srow) * DHEAD + c4 * 4]);
    *reinterpret_cast<short4v*>(&t[srow][c4 * 4]) = v;
  }
  __syncthreads();
#pragma unroll
  for (int it = 0; it < 4; ++it) {
    int u = it * 256 + tid;
    int d = u >> 4, s4 = u & 15;
    short4v v;
#pragma unroll
    for (int j = 0; j < 4; ++j) v[j] = t[s4 * 4 + j][d];
    *reinterpret_cast<short4v*>(
        &Vt[((size_t)g * DHEAD + d) * S_LEN + s0 + s4 * 4]) = v;
  }
}

// ---------------- sliding-window attention (swapped-QK, packed P, GQA pair) ----
// Block = 64 q-rows x 2 heads of the SAME GQA group (8 waves, 512 threads):
// wave w -> head h0+(w>>2), rows q0b+(w&3)*16. All waves share one q-range ->
// block-uniform window, no guards; K/V staged ONCE per block serves 2 heads.
// LDS 48KB -> 3 blocks/CU (24 waves/CU).
__global__ __launch_bounds__(512, 6) void k_attn(const unsigned short* __restrict__ Qr,
                                                 const unsigned short* __restrict__ Kr,
                                                 const unsigned short* __restrict__ Vt,
                                                 unsigned short* __restrict__ AO) {
  __shared__ unsigned short Ks[2][64][64];   // 16 KB
  __shared__ unsigned short Vs[2][64][64];   // 16 KB
  __shared__ unsigned short Pl[8][16][64];   // 16 KB

  const int tid = threadIdx.x, w = tid >> 6, lane = tid & 63;
  const int l15 = lane & 15, lhi = lane >> 4;

  // XCD-chunked bijective swizzle: 1024 blocks, 128 consecutive logical ids
  // per XCD => 2 (b,hk) K/V working sets (~1 MB) per XCD L2.
  int p = blockIdx.x;
  int L = (p & 7) * 128 + (p >> 3);
  int g = L >> 6;                 // 16 groups: (b, hk)
  int b = g >> 3, hk = g & 7;
  int r_ = L & 63;
  int h0 = hk * 4 + (r_ >> 5) * 2;  // head pair base (within the GQA group)
  int q0b = (r_ & 31) * 64;         // block q base (64 rows)

  const int h = h0 + (w >> 2);      // this wave's head
  const int qw = q0b + (w & 3) * 16;  // this wave's q base

  const unsigned short* Qh = Qr + (size_t)(b * NHEAD + h) * S_LEN * DHEAD;
  const unsigned short* Kh = Kr + (size_t)(b * NKVH + hk) * S_LEN * DHEAD;
  const unsigned short* Vh = Vt + (size_t)(b * NKVH + hk) * DHEAD * S_LEN;

  short8 qf[2];
#pragma unroll
  for (int c = 0; c < 2; ++c)
    qf[c] = *reinterpret_cast<const short8*>(&Qh[(size_t)(qw + l15) * DHEAD + c * 32 + lhi * 8]);

  f32x4 o[4] = {};
  float den = 0.f;
  const int q = qw + l15;          // this lane's q-row (swapped layout)
  const int kvisLo = q - HALFW, kvisHi = q + HALFW;

  char* plbase = (char*)&Pl[w][0][0];
  const int swzp = (l15 & 7) << 4;

  // block-uniform window (union over 64 q-rows); tiles 64-aligned
  int klo = q0b - HALFW; if (klo < 0) klo = 0;
  klo &= ~63;
  int khi = q0b + 63 + HALFW; if (khi > S_LEN - 1) khi = S_LEN - 1;
  const int nt = ((khi + 1 - klo) + 63) >> 6;

  // stage one 64-key tile: 512 threads -> one 16B unit each per K and V.
  auto stage = [&](int bufidx, int kbb) {
    int u = tid;
    int row = u >> 3, c16 = u & 7;
    int sc = c16 ^ (row & 7);
    __builtin_amdgcn_global_load_lds(
        (const __attribute__((address_space(1))) unsigned int*)(const void*)
            (Kh + (size_t)(kbb + row) * DHEAD + sc * 8),
        (__attribute__((address_space(3))) unsigned int*)(void*)
            ((char*)&Ks[bufidx][0][0] + u * 16),
        16, 0, 0);
    __builtin_amdgcn_global_load_lds(
        (const __attribute__((address_space(1))) unsigned int*)(const void*)
            (Vh + (size_t)row * S_LEN + kbb + sc * 8),
        (__attribute__((address_space(3))) unsigned int*)(void*)
            ((char*)&Vs[bufidx][0][0] + u * 16),
        16, 0, 0);
  };

  int cur = 0;
  stage(0, klo);
  __syncthreads();

  for (int t = 0; t < nt; ++t) {
    const int kb = klo + t * 64;
    if (t + 1 < nt) stage(cur ^ 1, kb + 64);   // prefetch next tile

    // ---- QK^T (swapped): C[key][q], lane holds q=l15, keys 16hh+4lhi+r ----
    f32x4 sacc[4] = {};
    __builtin_amdgcn_s_setprio(1);
#pragma unroll
    for (int hh = 0; hh < 4; ++hh) {
      int kr = hh * 16 + l15;
      const char* kbase = (const char*)&Ks[cur][0][0] + kr * 128;
      short8 kf0 = *reinterpret_cast<const short8*>(kbase + ((lhi ^ (kr & 7)) * 16));
      short8 kf1 = *reinterpret_cast<const short8*>(kbase + (((4 + lhi) ^ (kr & 7)) * 16));
      sacc[hh] = __builtin_amdgcn_mfma_f32_16x16x32_bf16(kf0, qf[0], sacc[hh], 0, 0, 0);
      sacc[hh] = __builtin_amdgcn_mfma_f32_16x16x32_bf16(kf1, qf[1], sacc[hh], 0, 0, 0);
    }
    __builtin_amdgcn_s_setprio(0);

    const bool inter = (kb >= qw + 15 - HALFW) && (kb + 63 <= qw + HALFW);
    if (inter) {
#pragma unroll
      for (int hh = 0; hh < 4; ++hh) {
        float p0 = __builtin_amdgcn_exp2f(sacc[hh][0]);
        float p1 = __builtin_amdgcn_exp2f(sacc[hh][1]);
        float p2 = __builtin_amdgcn_exp2f(sacc[hh][2]);
        float p3 = __builtin_amdgcn_exp2f(sacc[hh][3]);
        den += (p0 + p1) + (p2 + p3);
        u32x2 pw;
        pw[0] = cvt_pk_bf16(p0, p1);
        pw[1] = cvt_pk_bf16(p2, p3);
        *(u32x2*)(plbase + ((l15 * 128 + hh * 32 + lhi * 8) ^ swzp)) = pw;
      }
    } else {
#pragma unroll
      for (int hh = 0; hh < 4; ++hh) {
        float pp[4];
#pragma unroll
        for (int r = 0; r < 4; ++r) {
          int key = kb + hh * 16 + lhi * 4 + r;
          bool vis = (key >= kvisLo) && (key <= kvisHi);
          pp[r] = vis ? __builtin_amdgcn_exp2f(sacc[hh][r]) : 0.0f;
        }
        den += (pp[0] + pp[1]) + (pp[2] + pp[3]);
        u32x2 pw;
        pw[0] = cvt_pk_bf16(pp[0], pp[1]);
        pw[1] = cvt_pk_bf16(pp[2], pp[3]);
        *(u32x2*)(plbase + ((l15 * 128 + hh * 32 + lhi * 8) ^ swzp)) = pw;
      }
    }
    asm volatile("s_waitcnt lgkmcnt(0)" ::: "memory");
    __builtin_amdgcn_sched_barrier(0);

    // ---- PV: A = P (16q x 64k) from swizzled Pl, B = V from swizzled LDS ----
    short8 pf0 = *reinterpret_cast<const short8*>(plbase + ((l15 * 128 + lhi * 16) ^ swzp));
    short8 pf1 = *reinterpret_cast<const short8*>(plbase + ((l15 * 128 + 64 + lhi * 16) ^ swzp));
    __builtin_amdgcn_s_setprio(1);
#pragma unroll
    for (int c = 0; c < 4; ++c) {
      int d = c * 16 + l15;
      const char* vbase = (const char*)&Vs[cur][0][0] + d * 128;
      short8 vf0 = *reinterpret_cast<const short8*>(vbase + ((lhi ^ (d & 7)) * 16));
      short8 vf1 = *reinterpret_cast<const short8*>(vbase + (((4 + lhi) ^ (d & 7)) * 16));
      o[c] = __builtin_amdgcn_mfma_f32_16x16x32_bf16(pf0, vf0, o[c], 0, 0, 0);
      o[c] = __builtin_amdgcn_mfma_f32_16x16x32_bf16(pf1, vf1, o[c], 0, 0, 0);
    }
    __builtin_amdgcn_s_setprio(0);

    __syncthreads();   // drains vmcnt (next-tile stage) + protects buffers
    cur ^= 1;
  }

  // ---- final denominator: reduce across the 4 lhi copies of each q-row ----
  den += __shfl_xor(den, 16);
  den += __shfl_xor(den, 32);

#pragma unroll
  for (int r = 0; r < 4; ++r) {
    int qo = qw + lhi * 4 + r;
    float dr = __shfl(den, lhi * 4 + r, 64);   // den lives at lanes l15 == q-row
    float dinv = 1.0f / dr;
#pragma unroll
    for (int c = 0; c < 4; ++c)
      AO[(size_t)(b * S_LEN + qo) * HIDDEN + h * DHEAD + c * 16 + l15] = f2bf(o[c][r] * dinv);
  }
}

// ---------------- host ----------------
extern "C" void kernel_launch(void* const* d_in, const int* in_sizes, int n_in,
                              void* d_out, int out_size, void* d_ws, size_t ws_size,
                              hipStream_t stream) {
  const float* hs   = (const float*)d_in[0];
  const float* cosb = (const float*)d_in[1];
  const float* sinb = (const float*)d_in[2];
  const float* Wq   = (const float*)d_in[3];
  const float* Wk   = (const float*)d_in[4];
  const float* Wv   = (const float*)d_in[5];
  const float* Wo   = (const float*)d_in[6];

  char* ws = (char*)d_ws;
  // ws layout (within the proven 62.92 MB envelope):
  unsigned short* Xbf  = (unsigned short*)(ws);                       // 16.78 MB
  unsigned short* Wqkv = (unsigned short*)(ws + 16777216);            // 12.58 MB
  unsigned short* Vt   = (unsigned short*)(ws + 29360128);            //  4.19 MB
  unsigned short* AO   = (unsigned short*)(ws + 33554432);            // 16.78 MB
  unsigned short* Wob  = (unsigned short*)(ws + 54525952);            //  8.39 MB

  // Q/K/Vrow scratch lives in d_out (25.2 MB <= 33.5 MB); dead before the
  // output projection overwrites d_out.
  unsigned short* Qr   = (unsigned short*)d_out;                      // 16.78 MB
  unsigned short* Kr   = Qr + (size_t)BATCH * NKVH * S_LEN * DHEAD * 4; // 4.19 MB
  unsigned short* Vrow = Kr + (size_t)BATCH * NKVH * S_LEN * DHEAD;     // 4.19 MB

  // converts (single merged launch)
  k_cvt5<<<2048, 256, 0, stream>>>(hs, Wq, Wk, Wv, Wo,
                                   Xbf, Wqkv, Wqkv + 4194304, Wqkv + 5242880, Wob);

  // QKV projection (4096 x 2048) @ (3072 x 2048)^T with fused RoPE/head-split
  k_gemm_bt<2><<<dim3(3072 / 128, 4096 / 128), 256, 0, stream>>>(
      Xbf, Wqkv, nullptr, cosb, sinb, Qr, Kr, Vrow, 4096, 3072, 2048);

  // V transpose (b,hk,s,d) -> (b,hk,d,s)
  k_vt<<<dim3(S_LEN / 64, BATCH * NKVH), 256, 0, stream>>>(Vrow, Vt);

  // attention: 1024 blocks x 512 threads (XCD-swizzled inside),
  // 64 q-rows x 2 GQA-paired heads per block
  k_attn<<<BATCH * (NHEAD / 2) * (S_LEN / 64), 512, 0, stream>>>(Qr, Kr, Vt, AO);

  // output projection: (4096 x 2048) @ (2048 x 2048)^T -> f32 d_out
  k_gemm_bt<1><<<dim3(2048 / 128, 4096 / 128), 256, 0, stream>>>(
      AO, Wob, d_out, nullptr, nullptr, nullptr, nullptr, nullptr, 4096, 2048, 2048);
}